// Round 10
// baseline (132.731 us; speedup 1.0000x reference)
//
#include <hip/hip_runtime.h>
#include <math.h>

typedef short bf16x8 __attribute__((ext_vector_type(8)));
typedef float f32x4 __attribute__((ext_vector_type(4)));

#define MFMA16(a, b, c) __builtin_amdgcn_mfma_f32_16x16x32_bf16((a), (b), (c), 0, 0, 0)

#define TWO_PI_F 6.28318530717958647692f

// ---------------- ws layout: FRAGMENT-ORDERED bf16 weights ----------------
// every frag = 512 ushort = 64 lanes x 16B, loaded as one coalesced 1KB instr.
// pfw : [c:8][half:2][n_t:8][kk:9] frags ; n = half*128+n_t*16+cfr, k = kk*32+kg*8+e
// w1  : [n16:16][kk:6] frags          ; n = n16*16+cfr, k = kk*32+kg*8+e (0 for k>=168)
// expw: [n16:8] frags                 ; n = n16*16+cfr, k = kg*8+e
// wout: [kk:9] frags                  ; n = cfr,        k = kk*32+kg*8+e
#define PFW_OFF    0
#define PFW_ELEMS  (8 * 2 * 8 * 9 * 512)      // 589,824
#define W1_OFF     (PFW_OFF + PFW_ELEMS)
#define W1_ELEMS   (16 * 6 * 512)             // 49,152
#define EXPW_OFF   (W1_OFF + W1_ELEMS)
#define EXPW_ELEMS (8 * 512)                  // 4,096
#define WOUT_OFF   (EXPW_OFF + EXPW_ELEMS)
#define WOUT_ELEMS (9 * 512)                  // 4,608
#define TOTAL_ELEMS (WOUT_OFF + WOUT_ELEMS)   // 647,680 -> 1,295,360 bytes

#define MAIN_THREADS 512
#define TILE_B 64

__device__ __forceinline__ unsigned short f2bf(float x) {
    unsigned int u = __float_as_uint(x);
    unsigned int r = u + 0x7fffu + ((u >> 16) & 1u);   // RNE
    return (unsigned short)(r >> 16);
}

__device__ __forceinline__ float elu_f(float x) {
    return x > 0.0f ? x : (expf(x) - 1.0f);
}

// ---------------- weight conversion to fragment order (every launch) ----------------
__global__ __launch_bounds__(256) void prep_weights(
    const float* __restrict__ exp_w, const float* __restrict__ w1,
    const float* __restrict__ pf_w, const float* __restrict__ w_out,
    unsigned short* __restrict__ wsb)
{
    int i = blockIdx.x * blockDim.x + threadIdx.x;
    if (i >= TOTAL_ELEMS) return;
    float v;
    if (i < W1_OFF) {
        int f = i >> 9, e512 = i & 511;
        int ln = e512 >> 3, e = e512 & 7;
        int kgp = ln >> 4, cf = ln & 15;
        int kk = f % 9; int rest = f / 9;
        int n_t = rest & 7; int rest2 = rest >> 3;
        int half = rest2 & 1; int c = rest2 >> 1;
        int n = half * 128 + n_t * 16 + cf;
        int k = kk * 32 + kgp * 8 + e;            // < 288 always
        v = pf_w[((size_t)(c * 256 + n)) * 288 + k];
    } else if (i < EXPW_OFF) {
        int j = i - W1_OFF;
        int f = j >> 9, e512 = j & 511;
        int ln = e512 >> 3, e = e512 & 7;
        int kgp = ln >> 4, cf = ln & 15;
        int kk = f % 6; int n16 = f / 6;
        int n = n16 * 16 + cf;
        int k = kk * 32 + kgp * 8 + e;
        v = (k < 168) ? w1[n * 168 + k] : 0.0f;
    } else if (i < WOUT_OFF) {
        int j = i - EXPW_OFF;
        int n16 = j >> 9; int e512 = j & 511;
        int ln = e512 >> 3, e = e512 & 7;
        int kgp = ln >> 4, cf = ln & 15;
        v = exp_w[(n16 * 16 + cf) * 32 + kgp * 8 + e];
    } else {
        int j = i - WOUT_OFF;
        int kk = j >> 9; int e512 = j & 511;
        int ln = e512 >> 3, e = e512 & 7;
        int kgp = ln >> 4, cf = ln & 15;
        int k = kk * 32 + kgp * 8 + e;            // < 288
        v = w_out[cf * 288 + k];
    }
    wsb[i] = f2bf(v);
}

// ---------------- fused MFMA kernel: 64 rows/block, 8 waves ----------------
// Stage C: K sliced into 3 passes of 96 (af[4][3] = 48 VGPRs) so the register
// A-tile fits the ~128-arch-VGPR allocator cap observed in R2/R4-R7/R9.
__global__ __launch_bounds__(MAIN_THREADS, 2) void pfnn_mfma(
    const float* __restrict__ inputs,
    const float* __restrict__ exp_b,
    const float* __restrict__ cp,
    const float* __restrict__ b1,
    const float* __restrict__ pf_b,
    const float* __restrict__ b_out,
    const unsigned short* __restrict__ wsb,
    float* __restrict__ out, int B)
{
    // buf1: X1 = [expanded(0:128) | phase_nodes(128:136) | state(136:168) | 0(168:200)]
    //       later reused as Xout = [h2(0:256) | state(256:288)]
    // buf2: X2 = [h1(0:256) | state(256:288)]
    __shared__ __align__(16) unsigned short buf1[TILE_B * 296];
    __shared__ __align__(16) unsigned short buf2[TILE_B * 296];
    __shared__ float sWcT[8][TILE_B];          // blend weight per expert per row

    const unsigned short* pfwb  = wsb + PFW_OFF;
    const unsigned short* w1b   = wsb + W1_OFF;
    const unsigned short* expwb = wsb + EXPW_OFF;
    const unsigned short* woutb = wsb + WOUT_OFF;

    const int t    = threadIdx.x;
    const int w    = t >> 6;        // wave 0..7
    const int lane = t & 63;
    const int cfr  = lane & 15;     // A-row / B-col / C-col index
    const int kg   = lane >> 4;     // k-group 0..3
    const int b0   = blockIdx.x * TILE_B;

    // ---- staging: inputs -> LDS (state scattered to all concat positions) ----
    for (int i = t; i < TILE_B * 32; i += MAIN_THREADS) {
        int row = i >> 5, j = i & 31;
        int grow = b0 + row;
        float v = (grow < B) ? inputs[(size_t)grow * 33 + 1 + j] : 0.0f;
        unsigned short bv = f2bf(v);
        buf1[row * 296 + 136 + j] = bv;   // X1 state
        buf1[row * 296 + 256 + j] = bv;   // Xout state
        buf2[row * 296 + 256 + j] = bv;   // X2 state
        buf1[row * 296 + 168 + j] = 0;    // X1 zero pad 168..199
    }
    // ---- per-row Catmull-Rom phase weights + phase nodes ----
    if (t < TILE_B) {
        int grow = b0 + t;
        float ph = (grow < B) ? inputs[(size_t)grow * 33] : 0.0f;
        float p = fmodf(ph, TWO_PI_F);
        if (p < 0.0f) p += TWO_PI_F;
        float pos = p * (8.0f / TWO_PI_F);
        int base = (int)floorf(pos);
        float tt = pos - (float)base;
        base &= 7;
        float t2 = tt * tt, t3 = t2 * tt;
        float cw0 = -0.5f * tt + t2 - 0.5f * t3;
        float cw1 = 1.0f - 2.5f * t2 + 1.5f * t3;
        float cw2 = 0.5f * tt + 2.0f * t2 - 1.5f * t3;
        float cw3 = -0.5f * t2 + 0.5f * t3;
        int i0 = (base + 7) & 7, i1 = base, i2 = (base + 1) & 7, i3 = (base + 2) & 7;
        #pragma unroll
        for (int c = 0; c < 8; ++c) sWcT[c][t] = 0.0f;
        sWcT[i0][t] += cw0;
        sWcT[i1][t] += cw1;
        sWcT[i2][t] += cw2;
        sWcT[i3][t] += cw3;
        #pragma unroll
        for (int j = 0; j < 8; ++j) {
            float pn = cw0 * cp[i0 * 8 + j] + cw1 * cp[i1 * 8 + j]
                     + cw2 * cp[i2 * 8 + j] + cw3 * cp[i3 * 8 + j];
            buf1[t * 296 + 128 + j] = f2bf(pn);
        }
    }
    __syncthreads();

    // ---- stage A: expanded = elu(state @ exp_w.T + exp_b)   N=128, K=32 ----
    {
        const int n0 = w * 16;                 // 8 waves x 16 = 128
        bf16x8 bw = *(const bf16x8*)(expwb + w * 512 + lane * 8);
        const f32x4 zero = {0.f, 0.f, 0.f, 0.f};
        f32x4 acc[4];
        #pragma unroll
        for (int m = 0; m < 4; ++m) {
            bf16x8 a = *(const bf16x8*)&buf1[(m * 16 + cfr) * 296 + 136 + kg * 8];
            acc[m] = MFMA16(a, bw, zero);
        }
        float bias = exp_b[n0 + cfr];
        #pragma unroll
        for (int m = 0; m < 4; ++m)
            #pragma unroll
            for (int r = 0; r < 4; ++r) {
                int row = m * 16 + kg * 4 + r;
                buf1[row * 296 + n0 + cfr] = f2bf(elu_f(acc[m][r] + bias));
            }
    }
    __syncthreads();

    // ---- stage B: h1 = elu(X1 @ w1.T + b1)   N=256, K=192 (padded) ----
    {
        const int n0 = w * 32;                 // 8 waves x 32 = 256
        f32x4 acc[2][4];
        #pragma unroll
        for (int nt = 0; nt < 2; ++nt)
            #pragma unroll
            for (int m = 0; m < 4; ++m)
                acc[nt][m] = (f32x4){0.f, 0.f, 0.f, 0.f};
        #pragma unroll
        for (int kk = 0; kk < 6; ++kk) {
            bf16x8 a[4];
            #pragma unroll
            for (int m = 0; m < 4; ++m)
                a[m] = *(const bf16x8*)&buf1[(m * 16 + cfr) * 296 + kk * 32 + kg * 8];
            #pragma unroll
            for (int nt = 0; nt < 2; ++nt) {
                bf16x8 bw = *(const bf16x8*)(w1b + ((w * 2 + nt) * 6 + kk) * 512 + lane * 8);
                #pragma unroll
                for (int m = 0; m < 4; ++m)
                    acc[nt][m] = MFMA16(a[m], bw, acc[nt][m]);
            }
        }
        #pragma unroll
        for (int nt = 0; nt < 2; ++nt) {
            float bias = b1[n0 + nt * 16 + cfr];
            #pragma unroll
            for (int m = 0; m < 4; ++m)
                #pragma unroll
                for (int r = 0; r < 4; ++r) {
                    int row = m * 16 + kg * 4 + r;
                    buf2[row * 296 + n0 + nt * 16 + cfr] = f2bf(elu_f(acc[nt][m][r] + bias));
                }
        }
    }
    __syncthreads();

    // ---- stage C: 8-expert layer; K-sliced reg A-tile, coalesced 1KB b-frags ----
    // wave w owns cols n = half*128 + w*16 + cfr, all 64 rows. 3 passes x 96 k.
    // blend linearity: h2 = sum_pass sum_c wc*z^pass + sum_c wc*pfb (pass 0 only).
    {
        #pragma unroll
        for (int half = 0; half < 2; ++half) {
            f32x4 h2acc[4];
            #pragma unroll
            for (int m = 0; m < 4; ++m) h2acc[m] = (f32x4){0.f, 0.f, 0.f, 0.f};

            #pragma unroll
            for (int pass = 0; pass < 3; ++pass) {
                bf16x8 af[4][3];               // 48 VGPRs: rows 0..63 x k-slice 96
                #pragma unroll
                for (int m = 0; m < 4; ++m)
                    #pragma unroll
                    for (int q = 0; q < 3; ++q)
                        af[m][q] = *(const bf16x8*)
                            &buf2[(m * 16 + cfr) * 296 + (pass * 3 + q) * 32 + kg * 8];

                for (int c = 0; c < 8; ++c) {
                    const unsigned short* wp =
                        pfwb + (size_t)(((c * 2 + half) * 8 + w) * 9 + pass * 3) * 512 + lane * 8;
                    f32x4 z[4];
                    #pragma unroll
                    for (int m = 0; m < 4; ++m) z[m] = (f32x4){0.f, 0.f, 0.f, 0.f};
                    #pragma unroll
                    for (int q = 0; q < 3; ++q) {
                        bf16x8 bw = *(const bf16x8*)(wp + q * 512);
                        #pragma unroll
                        for (int m = 0; m < 4; ++m)
                            z[m] = MFMA16(af[m][q], bw, z[m]);
                    }
                    float pfb = (pass == 0) ? pf_b[c * 256 + half * 128 + w * 16 + cfr] : 0.0f;
                    #pragma unroll
                    for (int m = 0; m < 4; ++m) {
                        f32x4 wcv = *(const f32x4*)&sWcT[c][m * 16 + kg * 4];
                        #pragma unroll
                        for (int r = 0; r < 4; ++r)
                            h2acc[m][r] += wcv[r] * (z[m][r] + pfb);
                    }
                }
            }
            // epilogue: h2 cols half*128 + w*16 + cfr -> buf1
            #pragma unroll
            for (int m = 0; m < 4; ++m)
                #pragma unroll
                for (int r = 0; r < 4; ++r) {
                    int row = m * 16 + kg * 4 + r;
                    buf1[row * 296 + half * 128 + w * 16 + cfr] = f2bf(elu_f(h2acc[m][r]));
                }
        }
    }
    __syncthreads();

    // ---- stage D: out = Xout @ w_out.T + b_out   N=16, K=288 ----
    if (w < 4) {
        f32x4 acc = {0.f, 0.f, 0.f, 0.f};
        #pragma unroll
        for (int kk = 0; kk < 9; ++kk) {
            bf16x8 a  = *(const bf16x8*)&buf1[(w * 16 + cfr) * 296 + kk * 32 + kg * 8];
            bf16x8 bw = *(const bf16x8*)(woutb + kk * 512 + lane * 8);
            acc = MFMA16(a, bw, acc);
        }
        float bias = b_out[cfr];
        #pragma unroll
        for (int r = 0; r < 4; ++r) {
            int grow = b0 + w * 16 + kg * 4 + r;
            if (grow < B) out[(size_t)grow * 16 + cfr] = acc[r] + bias;
        }
    }
}

// ---------------- fp32 fallback (round-1 kernel, direct pf_w reads) ----------------
#define FB_TILE 16
#define FB_THREADS 256

__global__ __launch_bounds__(FB_THREADS) void pfnn_fused_f32(
    const float* __restrict__ inputs,
    const float* __restrict__ exp_w, const float* __restrict__ exp_b,
    const float* __restrict__ cp,
    const float* __restrict__ w1, const float* __restrict__ b1,
    const float* __restrict__ pf_w, const float* __restrict__ pf_b,
    const float* __restrict__ w_out, const float* __restrict__ b_out,
    float* __restrict__ out, int B)
{
    __shared__ float sState[FB_TILE][36];
    __shared__ float sFI[FB_TILE][172];
    __shared__ float sH2in[FB_TILE][292];
    __shared__ float sH2[FB_TILE][260];
    __shared__ float sWc[FB_TILE][8];
    __shared__ float sPhase[FB_TILE];

    const int t = threadIdx.x;
    const int b0 = blockIdx.x * FB_TILE;
    const int nb = min(FB_TILE, B - b0);

    for (int i = t; i < nb * 33; i += FB_THREADS) {
        int b = i / 33, j = i % 33;
        float v = inputs[(size_t)(b0 + b) * 33 + j];
        if (j == 0) sPhase[b] = v;
        else { sState[b][j-1] = v; sFI[b][136 + j-1] = v; sH2in[b][256 + j-1] = v; }
    }
    for (int i = nb * 33 + t; i < FB_TILE * 33; i += FB_THREADS) {
        int b = i / 33, j = i % 33;
        if (j == 0) sPhase[b] = 0.0f;
        else { sState[b][j-1] = 0.0f; sFI[b][136 + j-1] = 0.0f; sH2in[b][256 + j-1] = 0.0f; }
    }
    __syncthreads();
    {
        const int o = t & 127;
        const int bh = t >> 7;
        const float4* wrow = reinterpret_cast<const float4*>(exp_w + o * 32);
        float4 wv[8];
        #pragma unroll
        for (int q = 0; q < 8; ++q) wv[q] = wrow[q];
        const float bias = exp_b[o];
        for (int bi = bh; bi < FB_TILE; bi += 2) {
            float acc = bias;
            #pragma unroll
            for (int q = 0; q < 8; ++q) {
                acc += wv[q].x * sState[bi][q*4+0] + wv[q].y * sState[bi][q*4+1]
                     + wv[q].z * sState[bi][q*4+2] + wv[q].w * sState[bi][q*4+3];
            }
            sFI[bi][o] = elu_f(acc);
        }
    }
    if (t < FB_TILE) {
        float p = fmodf(sPhase[t], TWO_PI_F);
        if (p < 0.0f) p += TWO_PI_F;
        float pos = p * (8.0f / TWO_PI_F);
        int base = (int)floorf(pos);
        float tt = pos - (float)base;
        base &= 7;
        float t2 = tt*tt, t3 = t2*tt;
        float cw0 = -0.5f*tt + t2 - 0.5f*t3;
        float cw1 = 1.0f - 2.5f*t2 + 1.5f*t3;
        float cw2 = 0.5f*tt + 2.0f*t2 - 1.5f*t3;
        float cw3 = -0.5f*t2 + 0.5f*t3;
        int i0 = (base+7)&7, i1 = base, i2 = (base+1)&7, i3 = (base+2)&7;
        #pragma unroll
        for (int c = 0; c < 8; ++c) sWc[t][c] = 0.0f;
        sWc[t][i0] += cw0; sWc[t][i1] += cw1; sWc[t][i2] += cw2; sWc[t][i3] += cw3;
        #pragma unroll
        for (int j = 0; j < 8; ++j)
            sFI[t][128 + j] = cw0*cp[i0*8+j] + cw1*cp[i1*8+j] + cw2*cp[i2*8+j] + cw3*cp[i3*8+j];
    }
    __syncthreads();
    {
        const int o = t;
        float acc[FB_TILE];
        const float bias = b1[o];
        #pragma unroll
        for (int b = 0; b < FB_TILE; ++b) acc[b] = bias;
        const float* wrow = w1 + o * 168;
        for (int k4 = 0; k4 < 42; ++k4) {
            float4 wv = *reinterpret_cast<const float4*>(wrow + k4 * 4);
            #pragma unroll
            for (int b = 0; b < FB_TILE; ++b) {
                float4 a = *reinterpret_cast<const float4*>(&sFI[b][k4 * 4]);
                acc[b] += wv.x*a.x + wv.y*a.y + wv.z*a.z + wv.w*a.w;
            }
        }
        #pragma unroll
        for (int b = 0; b < FB_TILE; ++b) sH2in[b][o] = elu_f(acc[b]);
    }
    __syncthreads();
    {
        const int o = t;
        float h2acc[FB_TILE];
        #pragma unroll
        for (int b = 0; b < FB_TILE; ++b) h2acc[b] = 0.0f;
        for (int g = 0; g < 2; ++g) {
            float zacc[FB_TILE][4];
            #pragma unroll
            for (int b = 0; b < FB_TILE; ++b)
                #pragma unroll
                for (int ci = 0; ci < 4; ++ci) zacc[b][ci] = 0.0f;
            for (int k4 = 0; k4 < 72; ++k4) {
                float wv[4][4];
                #pragma unroll
                for (int ci = 0; ci < 4; ++ci) {
                    float4 v = *reinterpret_cast<const float4*>(
                        pf_w + (size_t)((g*4+ci) * 256 + o) * 288 + k4 * 4);
                    wv[ci][0]=v.x; wv[ci][1]=v.y; wv[ci][2]=v.z; wv[ci][3]=v.w;
                }
                #pragma unroll
                for (int b = 0; b < FB_TILE; ++b) {
                    float4 a = *reinterpret_cast<const float4*>(&sH2in[b][k4 * 4]);
                    #pragma unroll
                    for (int ci = 0; ci < 4; ++ci)
                        zacc[b][ci] += a.x*wv[ci][0] + a.y*wv[ci][1] + a.z*wv[ci][2] + a.w*wv[ci][3];
                }
            }
            #pragma unroll
            for (int b = 0; b < FB_TILE; ++b)
                #pragma unroll
                for (int ci = 0; ci < 4; ++ci)
                    h2acc[b] += sWc[b][g*4+ci] * (zacc[b][ci] + pf_b[(g*4+ci) * 256 + o]);
        }
        #pragma unroll
        for (int b = 0; b < FB_TILE; ++b) sH2[b][o] = elu_f(h2acc[b]);
    }
    __syncthreads();
    {
        const int b = t >> 4;
        const int j = t & 15;
        const float* wrow = w_out + j * 288;
        float acc = b_out[j];
        for (int k4 = 0; k4 < 64; ++k4) {
            float4 wv = *reinterpret_cast<const float4*>(wrow + k4 * 4);
            float4 a = *reinterpret_cast<const float4*>(&sH2[b][k4 * 4]);
            acc += wv.x*a.x + wv.y*a.y + wv.z*a.z + wv.w*a.w;
        }
        #pragma unroll
        for (int j2 = 0; j2 < 32; ++j2) acc += wrow[256 + j2] * sState[b][j2];
        if (b < nb) out[(size_t)(b0 + b) * 16 + j] = acc;
    }
}

extern "C" void kernel_launch(void* const* d_in, const int* in_sizes, int n_in,
                              void* d_out, int out_size, void* d_ws, size_t ws_size,
                              hipStream_t stream) {
    const float* inputs = (const float*)d_in[0];
    const float* exp_w  = (const float*)d_in[1];
    const float* exp_b  = (const float*)d_in[2];
    const float* cp     = (const float*)d_in[3];
    const float* w1     = (const float*)d_in[4];
    const float* b1     = (const float*)d_in[5];
    const float* pf_w   = (const float*)d_in[6];
    const float* pf_b   = (const float*)d_in[7];
    const float* w_out  = (const float*)d_in[8];
    const float* b_out  = (const float*)d_in[9];
    float* out = (float*)d_out;

    const int B = in_sizes[0] / 33;

    if (d_ws != nullptr && ws_size >= (size_t)TOTAL_ELEMS * sizeof(unsigned short)) {
        unsigned short* wsb = (unsigned short*)d_ws;
        prep_weights<<<(TOTAL_ELEMS + 255) / 256, 256, 0, stream>>>(
            exp_w, w1, pf_w, w_out, wsb);
        pfnn_mfma<<<(B + TILE_B - 1) / TILE_B, MAIN_THREADS, 0, stream>>>(
            inputs, exp_b, cp, b1, pf_b, b_out, wsb, out, B);
    } else {
        pfnn_fused_f32<<<(B + FB_TILE - 1) / FB_TILE, FB_THREADS, 0, stream>>>(
            inputs, exp_w, exp_b, cp, w1, b1, pf_w, pf_b, w_out, b_out, out, B);
    }
}

// Round 11
// 38.822 us; speedup vs baseline: 3.4189x; 3.4189x over previous
//
#include <hip/hip_runtime.h>
#include <math.h>

typedef short bf16x8 __attribute__((ext_vector_type(8)));
typedef float f32x4 __attribute__((ext_vector_type(4)));

#define MFMA16(a, b, c) __builtin_amdgcn_mfma_f32_16x16x32_bf16((a), (b), (c), 0, 0, 0)

#define TWO_PI_F 6.28318530717958647692f

// ---------------- ws layout: FRAGMENT-ORDERED bf16 weights ----------------
// every frag = 512 ushort = 64 lanes x 16B, loaded as one coalesced 1KB instr.
// pfw : [c:8][half:2][n_t:8][kk:9] frags ; n = half*128+n_t*16+cfr, k = kk*32+kg*8+e
// w1  : [n16:16][kk:6] frags          ; n = n16*16+cfr, k = kk*32+kg*8+e (0 for k>=168)
// expw: [n16:8] frags                 ; n = n16*16+cfr, k = kg*8+e
// wout: [kk:9] frags                  ; n = cfr,        k = kk*32+kg*8+e
#define PFW_OFF    0
#define PFW_ELEMS  (8 * 2 * 8 * 9 * 512)      // 589,824
#define W1_OFF     (PFW_OFF + PFW_ELEMS)
#define W1_ELEMS   (16 * 6 * 512)             // 49,152
#define EXPW_OFF   (W1_OFF + W1_ELEMS)
#define EXPW_ELEMS (8 * 512)                  // 4,096
#define WOUT_OFF   (EXPW_OFF + EXPW_ELEMS)
#define WOUT_ELEMS (9 * 512)                  // 4,608
#define TOTAL_ELEMS (WOUT_OFF + WOUT_ELEMS)   // 647,680 -> 1,295,360 bytes

#define MAIN_THREADS 512
#define TILE_B 64

__device__ __forceinline__ unsigned short f2bf(float x) {
    unsigned int u = __float_as_uint(x);
    unsigned int r = u + 0x7fffu + ((u >> 16) & 1u);   // RNE
    return (unsigned short)(r >> 16);
}

__device__ __forceinline__ float elu_f(float x) {
    return x > 0.0f ? x : (expf(x) - 1.0f);
}

// ---------------- weight conversion to fragment order (every launch) ----------------
__global__ __launch_bounds__(256) void prep_weights(
    const float* __restrict__ exp_w, const float* __restrict__ w1,
    const float* __restrict__ pf_w, const float* __restrict__ w_out,
    unsigned short* __restrict__ wsb)
{
    int i = blockIdx.x * blockDim.x + threadIdx.x;
    if (i >= TOTAL_ELEMS) return;
    float v;
    if (i < W1_OFF) {
        int f = i >> 9, e512 = i & 511;
        int ln = e512 >> 3, e = e512 & 7;
        int kgp = ln >> 4, cf = ln & 15;
        int kk = f % 9; int rest = f / 9;
        int n_t = rest & 7; int rest2 = rest >> 3;
        int half = rest2 & 1; int c = rest2 >> 1;
        int n = half * 128 + n_t * 16 + cf;
        int k = kk * 32 + kgp * 8 + e;            // < 288 always
        v = pf_w[((size_t)(c * 256 + n)) * 288 + k];
    } else if (i < EXPW_OFF) {
        int j = i - W1_OFF;
        int f = j >> 9, e512 = j & 511;
        int ln = e512 >> 3, e = e512 & 7;
        int kgp = ln >> 4, cf = ln & 15;
        int kk = f % 6; int n16 = f / 6;
        int n = n16 * 16 + cf;
        int k = kk * 32 + kgp * 8 + e;
        v = (k < 168) ? w1[n * 168 + k] : 0.0f;
    } else if (i < WOUT_OFF) {
        int j = i - EXPW_OFF;
        int n16 = j >> 9; int e512 = j & 511;
        int ln = e512 >> 3, e = e512 & 7;
        int kgp = ln >> 4, cf = ln & 15;
        v = exp_w[(n16 * 16 + cf) * 32 + kgp * 8 + e];
    } else {
        int j = i - WOUT_OFF;
        int kk = j >> 9; int e512 = j & 511;
        int ln = e512 >> 3, e = e512 & 7;
        int kgp = ln >> 4, cf = ln & 15;
        int k = kk * 32 + kgp * 8 + e;            // < 288
        v = w_out[cf * 288 + k];
    }
    wsb[i] = f2bf(v);
}

// ---------------- fused MFMA kernel: R3's exact structure, fragment-ordered weights ----------------
// R3 shape (124 VGPR, zero spill, proven). ONLY change vs R3: every weight load is a
// single coalesced 1KB fragment (base + frag*512 + lane*8) instead of a 64-segment
// 592B-stride gather — cuts stage-C L2 transactions ~4x and TA issue ~16x.
__global__ __launch_bounds__(MAIN_THREADS, 2) void pfnn_mfma(
    const float* __restrict__ inputs,
    const float* __restrict__ exp_b,
    const float* __restrict__ cp,
    const float* __restrict__ b1,
    const float* __restrict__ pf_b,
    const float* __restrict__ b_out,
    const unsigned short* __restrict__ wsb,
    float* __restrict__ out, int B)
{
    // buf1: X1 = [expanded(0:128) | phase_nodes(128:136) | state(136:168) | 0(168:200)]
    //       later reused as Xout = [h2(0:256) | state(256:288)]
    // buf2: X2 = [h1(0:256) | state(256:288)]
    __shared__ __align__(16) unsigned short buf1[TILE_B * 296];
    __shared__ __align__(16) unsigned short buf2[TILE_B * 296];
    __shared__ float sWcT[8][TILE_B];          // blend weight per expert per row

    const unsigned short* pfwb  = wsb + PFW_OFF;
    const unsigned short* w1b   = wsb + W1_OFF;
    const unsigned short* expwb = wsb + EXPW_OFF;
    const unsigned short* woutb = wsb + WOUT_OFF;

    const int t    = threadIdx.x;
    const int w    = t >> 6;        // wave 0..7
    const int lane = t & 63;
    const int cfr  = lane & 15;     // A-row / B-col / C-col index
    const int kg   = lane >> 4;     // k-group 0..3
    const int b0   = blockIdx.x * TILE_B;

    // ---- staging: inputs -> LDS (state scattered to all concat positions) ----
    for (int i = t; i < TILE_B * 32; i += MAIN_THREADS) {
        int row = i >> 5, j = i & 31;
        int grow = b0 + row;
        float v = (grow < B) ? inputs[(size_t)grow * 33 + 1 + j] : 0.0f;
        unsigned short bv = f2bf(v);
        buf1[row * 296 + 136 + j] = bv;   // X1 state
        buf1[row * 296 + 256 + j] = bv;   // Xout state
        buf2[row * 296 + 256 + j] = bv;   // X2 state
        buf1[row * 296 + 168 + j] = 0;    // X1 zero pad 168..199
    }
    // ---- per-row Catmull-Rom phase weights + phase nodes ----
    if (t < TILE_B) {
        int grow = b0 + t;
        float ph = (grow < B) ? inputs[(size_t)grow * 33] : 0.0f;
        float p = fmodf(ph, TWO_PI_F);
        if (p < 0.0f) p += TWO_PI_F;
        float pos = p * (8.0f / TWO_PI_F);
        int base = (int)floorf(pos);
        float tt = pos - (float)base;
        base &= 7;
        float t2 = tt * tt, t3 = t2 * tt;
        float cw0 = -0.5f * tt + t2 - 0.5f * t3;
        float cw1 = 1.0f - 2.5f * t2 + 1.5f * t3;
        float cw2 = 0.5f * tt + 2.0f * t2 - 1.5f * t3;
        float cw3 = -0.5f * t2 + 0.5f * t3;
        int i0 = (base + 7) & 7, i1 = base, i2 = (base + 1) & 7, i3 = (base + 2) & 7;
        #pragma unroll
        for (int c = 0; c < 8; ++c) sWcT[c][t] = 0.0f;
        sWcT[i0][t] += cw0;
        sWcT[i1][t] += cw1;
        sWcT[i2][t] += cw2;
        sWcT[i3][t] += cw3;
        #pragma unroll
        for (int j = 0; j < 8; ++j) {
            float pn = cw0 * cp[i0 * 8 + j] + cw1 * cp[i1 * 8 + j]
                     + cw2 * cp[i2 * 8 + j] + cw3 * cp[i3 * 8 + j];
            buf1[t * 296 + 128 + j] = f2bf(pn);
        }
    }
    __syncthreads();

    // ---- stage A: expanded = elu(state @ exp_w.T + exp_b)   N=128, K=32 ----
    {
        const int n0 = w * 16;                 // 8 waves x 16 = 128
        bf16x8 bw = *(const bf16x8*)(expwb + w * 512 + lane * 8);
        const f32x4 zero = {0.f, 0.f, 0.f, 0.f};
        f32x4 acc[4];
        #pragma unroll
        for (int m = 0; m < 4; ++m) {
            bf16x8 a = *(const bf16x8*)&buf1[(m * 16 + cfr) * 296 + 136 + kg * 8];
            acc[m] = MFMA16(a, bw, zero);
        }
        float bias = exp_b[n0 + cfr];
        #pragma unroll
        for (int m = 0; m < 4; ++m)
            #pragma unroll
            for (int r = 0; r < 4; ++r) {
                int row = m * 16 + kg * 4 + r;
                buf1[row * 296 + n0 + cfr] = f2bf(elu_f(acc[m][r] + bias));
            }
    }
    __syncthreads();

    // ---- stage B: h1 = elu(X1 @ w1.T + b1)   N=256, K=192 (padded) ----
    {
        const int n0 = w * 32;                 // 8 waves x 32 = 256
        f32x4 acc[2][4];
        #pragma unroll
        for (int nt = 0; nt < 2; ++nt)
            #pragma unroll
            for (int m = 0; m < 4; ++m)
                acc[nt][m] = (f32x4){0.f, 0.f, 0.f, 0.f};
        #pragma unroll
        for (int kk = 0; kk < 6; ++kk) {
            bf16x8 a[4];
            #pragma unroll
            for (int m = 0; m < 4; ++m)
                a[m] = *(const bf16x8*)&buf1[(m * 16 + cfr) * 296 + kk * 32 + kg * 8];
            #pragma unroll
            for (int nt = 0; nt < 2; ++nt) {
                bf16x8 bw = *(const bf16x8*)(w1b + ((w * 2 + nt) * 6 + kk) * 512 + lane * 8);
                #pragma unroll
                for (int m = 0; m < 4; ++m)
                    acc[nt][m] = MFMA16(a[m], bw, acc[nt][m]);
            }
        }
        #pragma unroll
        for (int nt = 0; nt < 2; ++nt) {
            float bias = b1[n0 + nt * 16 + cfr];
            #pragma unroll
            for (int m = 0; m < 4; ++m)
                #pragma unroll
                for (int r = 0; r < 4; ++r) {
                    int row = m * 16 + kg * 4 + r;
                    buf2[row * 296 + n0 + nt * 16 + cfr] = f2bf(elu_f(acc[nt][m][r] + bias));
                }
        }
    }
    __syncthreads();

    // ---- stage C: dense 8-expert phase-function layer (R3 loop shape) ----
    // wave w -> 32 cols (nt=0,1), all 64 rows; loop c -> kk -> {2 bw, 4 a, 8 MFMA}.
    // col-group g = w*2+nt -> fragment coords half = g>>3, n_t = g&7.
    {
        const int n0 = w * 32;
        const int g0 = w * 2;
        const size_t fb0 = (size_t)(((g0 >> 3) * 8 + (g0 & 7)) * 9) * 512 + lane * 8;
        const size_t fb1 = (size_t)((((g0 + 1) >> 3) * 8 + ((g0 + 1) & 7)) * 9) * 512 + lane * 8;

        f32x4 h2acc[2][4];
        #pragma unroll
        for (int nt = 0; nt < 2; ++nt)
            #pragma unroll
            for (int m = 0; m < 4; ++m)
                h2acc[nt][m] = (f32x4){0.f, 0.f, 0.f, 0.f};

        for (int c = 0; c < 8; ++c) {
            const unsigned short* wp0 = pfwb + (size_t)(c * 2 * 8 * 9) * 512 + fb0;
            const unsigned short* wp1 = pfwb + (size_t)(c * 2 * 8 * 9) * 512 + fb1;

            f32x4 z[2][4];
            #pragma unroll
            for (int nt = 0; nt < 2; ++nt)
                #pragma unroll
                for (int m = 0; m < 4; ++m)
                    z[nt][m] = (f32x4){0.f, 0.f, 0.f, 0.f};

            #pragma unroll
            for (int kk = 0; kk < 9; ++kk) {
                bf16x8 bw0 = *(const bf16x8*)(wp0 + kk * 512);
                bf16x8 bw1 = *(const bf16x8*)(wp1 + kk * 512);
                #pragma unroll
                for (int m = 0; m < 4; ++m) {
                    bf16x8 a = *(const bf16x8*)&buf2[(m * 16 + cfr) * 296 + kk * 32 + kg * 8];
                    z[0][m] = MFMA16(a, bw0, z[0][m]);
                    z[1][m] = MFMA16(a, bw1, z[1][m]);
                }
            }

            float pfb0 = pf_b[c * 256 + n0 + cfr];
            float pfb1 = pf_b[c * 256 + n0 + 16 + cfr];
            #pragma unroll
            for (int m = 0; m < 4; ++m) {
                f32x4 wcv = *(const f32x4*)&sWcT[c][m * 16 + kg * 4];
                #pragma unroll
                for (int r = 0; r < 4; ++r) {
                    h2acc[0][m][r] += wcv[r] * (z[0][m][r] + pfb0);
                    h2acc[1][m][r] += wcv[r] * (z[1][m][r] + pfb1);
                }
            }
        }
        // epilogue: h2 -> buf1 cols 0..255 (state already at 256..287)
        #pragma unroll
        for (int nt = 0; nt < 2; ++nt)
            #pragma unroll
            for (int m = 0; m < 4; ++m)
                #pragma unroll
                for (int r = 0; r < 4; ++r) {
                    int row = m * 16 + kg * 4 + r;
                    buf1[row * 296 + n0 + nt * 16 + cfr] = f2bf(elu_f(h2acc[nt][m][r]));
                }
    }
    __syncthreads();

    // ---- stage D: out = Xout @ w_out.T + b_out   N=16, K=288 ----
    if (w < 4) {
        f32x4 acc = {0.f, 0.f, 0.f, 0.f};
        #pragma unroll
        for (int kk = 0; kk < 9; ++kk) {
            bf16x8 a  = *(const bf16x8*)&buf1[(w * 16 + cfr) * 296 + kk * 32 + kg * 8];
            bf16x8 bw = *(const bf16x8*)(woutb + kk * 512 + lane * 8);
            acc = MFMA16(a, bw, acc);
        }
        float bias = b_out[cfr];
        #pragma unroll
        for (int r = 0; r < 4; ++r) {
            int grow = b0 + w * 16 + kg * 4 + r;
            if (grow < B) out[(size_t)grow * 16 + cfr] = acc[r] + bias;
        }
    }
}

// ---------------- fp32 fallback (round-1 kernel, direct pf_w reads) ----------------
#define FB_TILE 16
#define FB_THREADS 256

__global__ __launch_bounds__(FB_THREADS) void pfnn_fused_f32(
    const float* __restrict__ inputs,
    const float* __restrict__ exp_w, const float* __restrict__ exp_b,
    const float* __restrict__ cp,
    const float* __restrict__ w1, const float* __restrict__ b1,
    const float* __restrict__ pf_w, const float* __restrict__ pf_b,
    const float* __restrict__ w_out, const float* __restrict__ b_out,
    float* __restrict__ out, int B)
{
    __shared__ float sState[FB_TILE][36];
    __shared__ float sFI[FB_TILE][172];
    __shared__ float sH2in[FB_TILE][292];
    __shared__ float sH2[FB_TILE][260];
    __shared__ float sWc[FB_TILE][8];
    __shared__ float sPhase[FB_TILE];

    const int t = threadIdx.x;
    const int b0 = blockIdx.x * FB_TILE;
    const int nb = min(FB_TILE, B - b0);

    for (int i = t; i < nb * 33; i += FB_THREADS) {
        int b = i / 33, j = i % 33;
        float v = inputs[(size_t)(b0 + b) * 33 + j];
        if (j == 0) sPhase[b] = v;
        else { sState[b][j-1] = v; sFI[b][136 + j-1] = v; sH2in[b][256 + j-1] = v; }
    }
    for (int i = nb * 33 + t; i < FB_TILE * 33; i += FB_THREADS) {
        int b = i / 33, j = i % 33;
        if (j == 0) sPhase[b] = 0.0f;
        else { sState[b][j-1] = 0.0f; sFI[b][136 + j-1] = 0.0f; sH2in[b][256 + j-1] = 0.0f; }
    }
    __syncthreads();
    {
        const int o = t & 127;
        const int bh = t >> 7;
        const float4* wrow = reinterpret_cast<const float4*>(exp_w + o * 32);
        float4 wv[8];
        #pragma unroll
        for (int q = 0; q < 8; ++q) wv[q] = wrow[q];
        const float bias = exp_b[o];
        for (int bi = bh; bi < FB_TILE; bi += 2) {
            float acc = bias;
            #pragma unroll
            for (int q = 0; q < 8; ++q) {
                acc += wv[q].x * sState[bi][q*4+0] + wv[q].y * sState[bi][q*4+1]
                     + wv[q].z * sState[bi][q*4+2] + wv[q].w * sState[bi][q*4+3];
            }
            sFI[bi][o] = elu_f(acc);
        }
    }
    if (t < FB_TILE) {
        float p = fmodf(sPhase[t], TWO_PI_F);
        if (p < 0.0f) p += TWO_PI_F;
        float pos = p * (8.0f / TWO_PI_F);
        int base = (int)floorf(pos);
        float tt = pos - (float)base;
        base &= 7;
        float t2 = tt*tt, t3 = t2*tt;
        float cw0 = -0.5f*tt + t2 - 0.5f*t3;
        float cw1 = 1.0f - 2.5f*t2 + 1.5f*t3;
        float cw2 = 0.5f*tt + 2.0f*t2 - 1.5f*t3;
        float cw3 = -0.5f*t2 + 0.5f*t3;
        int i0 = (base+7)&7, i1 = base, i2 = (base+1)&7, i3 = (base+2)&7;
        #pragma unroll
        for (int c = 0; c < 8; ++c) sWc[t][c] = 0.0f;
        sWc[t][i0] += cw0; sWc[t][i1] += cw1; sWc[t][i2] += cw2; sWc[t][i3] += cw3;
        #pragma unroll
        for (int j = 0; j < 8; ++j)
            sFI[t][128 + j] = cw0*cp[i0*8+j] + cw1*cp[i1*8+j] + cw2*cp[i2*8+j] + cw3*cp[i3*8+j];
    }
    __syncthreads();
    {
        const int o = t;
        float acc[FB_TILE];
        const float bias = b1[o];
        #pragma unroll
        for (int b = 0; b < FB_TILE; ++b) acc[b] = bias;
        const float* wrow = w1 + o * 168;
        for (int k4 = 0; k4 < 42; ++k4) {
            float4 wv = *reinterpret_cast<const float4*>(wrow + k4 * 4);
            #pragma unroll
            for (int b = 0; b < FB_TILE; ++b) {
                float4 a = *reinterpret_cast<const float4*>(&sFI[b][k4 * 4]);
                acc[b] += wv.x*a.x + wv.y*a.y + wv.z*a.z + wv.w*a.w;
            }
        }
        #pragma unroll
        for (int b = 0; b < FB_TILE; ++b) sH2in[b][o] = elu_f(acc[b]);
    }
    __syncthreads();
    {
        const int o = t;
        float h2acc[FB_TILE];
        #pragma unroll
        for (int b = 0; b < FB_TILE; ++b) h2acc[b] = 0.0f;
        for (int g = 0; g < 2; ++g) {
            float zacc[FB_TILE][4];
            #pragma unroll
            for (int b = 0; b < FB_TILE; ++b)
                #pragma unroll
                for (int ci = 0; ci < 4; ++ci) zacc[b][ci] = 0.0f;
            for (int k4 = 0; k4 < 72; ++k4) {
                float wv[4][4];
                #pragma unroll
                for (int ci = 0; ci < 4; ++ci) {
                    float4 v = *reinterpret_cast<const float4*>(
                        pf_w + (size_t)((g*4+ci) * 256 + o) * 288 + k4 * 4);
                    wv[ci][0]=v.x; wv[ci][1]=v.y; wv[ci][2]=v.z; wv[ci][3]=v.w;
                }
                #pragma unroll
                for (int b = 0; b < FB_TILE; ++b) {
                    float4 a = *reinterpret_cast<const float4*>(&sH2in[b][k4 * 4]);
                    #pragma unroll
                    for (int ci = 0; ci < 4; ++ci)
                        zacc[b][ci] += a.x*wv[ci][0] + a.y*wv[ci][1] + a.z*wv[ci][2] + a.w*wv[ci][3];
                }
            }
            #pragma unroll
            for (int b = 0; b < FB_TILE; ++b)
                #pragma unroll
                for (int ci = 0; ci < 4; ++ci)
                    h2acc[b] += sWc[b][g*4+ci] * (zacc[b][ci] + pf_b[(g*4+ci) * 256 + o]);
        }
        #pragma unroll
        for (int b = 0; b < FB_TILE; ++b) sH2[b][o] = elu_f(h2acc[b]);
    }
    __syncthreads();
    {
        const int b = t >> 4;
        const int j = t & 15;
        const float* wrow = w_out + j * 288;
        float acc = b_out[j];
        for (int k4 = 0; k4 < 64; ++k4) {
            float4 wv = *reinterpret_cast<const float4*>(wrow + k4 * 4);
            float4 a = *reinterpret_cast<const float4*>(&sH2[b][k4 * 4]);
            acc += wv.x*a.x + wv.y*a.y + wv.z*a.z + wv.w*a.w;
        }
        #pragma unroll
        for (int j2 = 0; j2 < 32; ++j2) acc += wrow[256 + j2] * sState[b][j2];
        if (b < nb) out[(size_t)(b0 + b) * 16 + j] = acc;
    }
}

extern "C" void kernel_launch(void* const* d_in, const int* in_sizes, int n_in,
                              void* d_out, int out_size, void* d_ws, size_t ws_size,
                              hipStream_t stream) {
    const float* inputs = (const float*)d_in[0];
    const float* exp_w  = (const float*)d_in[1];
    const float* exp_b  = (const float*)d_in[2];
    const float* cp     = (const float*)d_in[3];
    const float* w1     = (const float*)d_in[4];
    const float* b1     = (const float*)d_in[5];
    const float* pf_w   = (const float*)d_in[6];
    const float* pf_b   = (const float*)d_in[7];
    const float* w_out  = (const float*)d_in[8];
    const float* b_out  = (const float*)d_in[9];
    float* out = (float*)d_out;

    const int B = in_sizes[0] / 33;

    if (d_ws != nullptr && ws_size >= (size_t)TOTAL_ELEMS * sizeof(unsigned short)) {
        unsigned short* wsb = (unsigned short*)d_ws;
        prep_weights<<<(TOTAL_ELEMS + 255) / 256, 256, 0, stream>>>(
            exp_w, w1, pf_w, w_out, wsb);
        pfnn_mfma<<<(B + TILE_B - 1) / TILE_B, MAIN_THREADS, 0, stream>>>(
            inputs, exp_b, cp, b1, pf_b, b_out, wsb, out, B);
    } else {
        pfnn_fused_f32<<<(B + FB_TILE - 1) / FB_TILE, FB_THREADS, 0, stream>>>(
            inputs, exp_w, exp_b, cp, w1, b1, pf_w, pf_b, w_out, b_out, out, B);
    }
}